// Round 3
// baseline (223.740 us; speedup 1.0000x reference)
//
#include <hip/hip_runtime.h>
#include <hip/hip_bf16.h>

// Problem constants (CausalSelfAttention_23768349016530)
#define B_  8
#define N_  1024
#define C_  768
#define H_  12
#define D_  64
#define C3  2304   // 3*C
#define C2  1536   // 2*C

typedef unsigned short ushort_t;
typedef __attribute__((ext_vector_type(8))) short bf16x8;   // 8 bf16 = 4 VGPR
typedef __attribute__((ext_vector_type(4))) float f32x4;    // MFMA 16x16 accumulator
typedef __attribute__((ext_vector_type(4))) unsigned int u32x4;
typedef __attribute__((ext_vector_type(2))) unsigned int u32x2;

__device__ __forceinline__ float bf2f(ushort_t u) {
    union { unsigned int i; float f; } v;
    v.i = ((unsigned int)u) << 16;
    return v.f;
}

__device__ __forceinline__ ushort_t f2bf(float f) {
    union { float f; unsigned int i; } v;
    v.f = f;
    unsigned int x = v.i;
    if ((x & 0x7f800000u) == 0x7f800000u && (x & 0x007fffffu))
        return (ushort_t)((x >> 16) | 0x0040u);   // quiet NaN
    return (ushort_t)((x + 0x7fffu + ((x >> 16) & 1u)) >> 16);  // RNE
}

__device__ __forceinline__ void st1(float* p, float v) { *p = v; }
__device__ __forceinline__ void st1(ushort_t* p, float v) { *p = f2bf(v); }

// ---------------------------------------------------------------------------
// fp32 -> bf16 elementwise (for x)
// ---------------------------------------------------------------------------
__global__ __launch_bounds__(256) void cvt_bf16(
    const float* __restrict__ X, ushort_t* __restrict__ Y, int n)
{
    int i = (blockIdx.x * 256 + threadIdx.x) * 4;
    if (i < n) {
        float4 f = *reinterpret_cast<const float4*>(X + i);
        ushort4 o;
        o.x = f2bf(f.x); o.y = f2bf(f.y); o.z = f2bf(f.z); o.w = f2bf(f.w);
        *reinterpret_cast<ushort4*>(Y + i) = o;
    }
}

// ---------------------------------------------------------------------------
// W[K][Nn] fp32  ->  WT[Nn][K] bf16   (32x32 LDS tile transpose)
// ---------------------------------------------------------------------------
__global__ __launch_bounds__(256) void transpose_to_bf16(
    const float* __restrict__ W, ushort_t* __restrict__ WT, int K, int Nn)
{
    __shared__ float t[32][33];
    const int n0 = blockIdx.x * 32, k0 = blockIdx.y * 32;
    const int tx = threadIdx.x & 31, ty = threadIdx.x >> 5;   // ty: 0..7
    #pragma unroll
    for (int i = 0; i < 4; ++i) {
        const int k = ty + i * 8;
        t[k][tx] = W[(size_t)(k0 + k) * Nn + n0 + tx];
    }
    __syncthreads();
    #pragma unroll
    for (int i = 0; i < 4; ++i) {
        const int n = ty + i * 8;
        WT[(size_t)(n0 + n) * K + k0 + tx] = f2bf(t[tx][n]);
    }
}

// ---------------------------------------------------------------------------
// MFMA GEMM: 128x128 tile, BK=64, 256 thr, XOR-swizzled LDS (conflict-free
// fragment reads; swizzle applied in the GLOBAL address so global_load_lds
// lane-linear dest still works: LDS slot s of row r holds k-granule s^(r&7)).
// SCALEQ folds 0.125*log2(e) into Q columns (attn then uses raw v_exp_f32,
// i.e. exp2, so softmax is unchanged mathematically). vtOut: V transposed.
// ---------------------------------------------------------------------------
#define GBK 64

__device__ __forceinline__ void gld_lds16(const ushort_t* g, ushort_t* lds) {
    __builtin_amdgcn_global_load_lds(
        (const __attribute__((address_space(1))) void*)g,
        (__attribute__((address_space(3))) void*)lds, 16, 0, 0);
}

template<typename TO, bool SCALEQ>
__global__ __launch_bounds__(256) void gemm_mfma(
    const ushort_t* __restrict__ A, const ushort_t* __restrict__ BT,
    const float* __restrict__ bias, TO* __restrict__ Y, int ldY,
    ushort_t* __restrict__ vtOut, int M, int K, int Nn)
{
    __shared__ ushort_t As[128 * GBK];   // [row][slot^], 128B rows
    __shared__ ushort_t Bs[128 * GBK];

    const int tid  = threadIdx.x;
    const int wave = tid >> 6;
    const int lane = tid & 63;
    const int row0 = blockIdx.y * 128;
    const int col0 = blockIdx.x * 128;
    const int wr   = (wave >> 1) * 64;
    const int wc   = (wave & 1) * 64;
    const int l15  = lane & 15;
    const int quad = lane >> 4;
    const int l7   = l15 & 7;

    // staging: lane -> (row = base + lane>>3, slot = lane&7); fetch granule
    // slot^row so that LDS slot s holds granule s^(r&7).
    const int srow = lane >> 3;                 // 0..7
    const int sg   = (lane & 7) ^ srow;         // data granule to fetch

    f32x4 acc[4][4] = {};

    for (int k0 = 0; k0 < K; k0 += GBK) {
        __syncthreads();
        #pragma unroll
        for (int it = 0; it < 4; ++it) {
            const int baseRow = wave * 32 + it * 8;           // wave-uniform
            const int r = baseRow + srow;
            gld_lds16(&A [(size_t)(row0 + r) * K + k0 + sg * 8], &As[baseRow * GBK]);
            gld_lds16(&BT[(size_t)(col0 + r) * K + k0 + sg * 8], &Bs[baseRow * GBK]);
        }
        __syncthreads();

        #pragma unroll
        for (int kc = 0; kc < 2; ++kc) {
            bf16x8 af[4], bf[4];
            #pragma unroll
            for (int i = 0; i < 4; ++i) {
                const int aslot = (kc * 4 + quad) ^ l7;
                af[i] = *reinterpret_cast<const bf16x8*>(
                    &As[(wr + i * 16 + l15) * GBK + aslot * 8]);
                bf[i] = *reinterpret_cast<const bf16x8*>(
                    &Bs[(wc + i * 16 + l15) * GBK + aslot * 8]);
            }
            #pragma unroll
            for (int i = 0; i < 4; ++i)
                #pragma unroll
                for (int j = 0; j < 4; ++j)
                    acc[i][j] = __builtin_amdgcn_mfma_f32_16x16x32_bf16(
                        af[i], bf[j], acc[i][j], 0, 0, 0);
        }
    }

    // per-wave-column-tile uniform Q-scale (columns < C_ are Q)
    // 0.125 * log2(e) so attention can use v_exp_f32 (base-2) directly.
    const float qs = (SCALEQ && (col0 + wc) < C_) ? 0.1803368801f : 1.0f;

    if (vtOut != nullptr && col0 >= C2) {
        // V part: write transposed vt[b][h][d][token]
        #pragma unroll
        for (int i = 0; i < 4; ++i) {
            const int r0 = row0 + wr + i * 16 + quad * 4;   // token base
            const int bb = r0 >> 10;
            const int n  = r0 & 1023;
            #pragma unroll
            for (int j = 0; j < 4; ++j) {
                const int c  = col0 + wc + j * 16 + l15;
                const int cv = c - C2;
                const int hh = cv >> 6, d = cv & 63;
                const float bv = bias[c];
                ushort4 o;
                o.x = f2bf(acc[i][j][0] + bv);
                o.y = f2bf(acc[i][j][1] + bv);
                o.z = f2bf(acc[i][j][2] + bv);
                o.w = f2bf(acc[i][j][3] + bv);
                *reinterpret_cast<ushort4*>(
                    &vtOut[((size_t)(bb * H_ + hh) * D_ + d) * N_ + n]) = o;
            }
        }
    } else {
        #pragma unroll
        for (int i = 0; i < 4; ++i) {
            const int r = row0 + wr + i * 16 + quad * 4;
            #pragma unroll
            for (int j = 0; j < 4; ++j) {
                const int c = col0 + wc + j * 16 + l15;
                const float bv = bias[c];
                #pragma unroll
                for (int t = 0; t < 4; ++t)
                    st1(&Y[(size_t)(r + t) * ldY + c], (acc[i][j][t] + bv) * qs);
            }
        }
    }
}

// ---------------------------------------------------------------------------
// MFMA attention, v3:
//  * swapped QK^T (mfma(K,Q)) so each lane holds P for its own query column
//    -> P packed to bf16 fully in-register; no P LDS round-trip, no Ps buffer
//    (LDS 36.9KB -> 18.4KB).
//  * v3 fix: the v2 `v_cvt_pk_bf16_f32` asm produced a pair-swapped PV
//    A-fragment (absmax 2.3e-2 matched the predicted pair-swap error).
//    Replaced with an explicit round-half-up bit-pack (identical semantics to
//    the round-0 quantizer) with unambiguous placement: T0 -> low half.
//  * PV consumes the packed words as the A-fragment under a key-slot
//    permutation; V is read with the SAME permutation (two 8B LDS reads), so
//    the key-sum is unchanged (valid because HW uses the identical slot->k
//    map for A and B fragments — proven by round-0's correctness).
//  * Q pre-scaled by 0.125*log2(e) in the QKV GEMM -> softmax numerator is a
//    single v_exp_f32 per element (2^(s*log2 e) = e^s).
//  * den accumulates the QUANTIZED bf16 P values (extracted from the packed
//    words) so each softmax row still sums to exactly 1 after bf16 PV.
//  * T14 async-stage split: next tile's K/V global loads issue before the
//    compute phase; LDS writes land after the next barrier.
// ---------------------------------------------------------------------------
#define LDT 72

__global__ __launch_bounds__(256) void attn_mfma(
    const ushort_t* __restrict__ qk, const ushort_t* __restrict__ vt,
    const int* __restrict__ pad_mask, ushort_t* __restrict__ y)
{
    __shared__ ushort_t KV[2 * 64 * LDT];
    ushort_t* const Ks  = KV;              // K tile  [key][d]
    ushort_t* const Vts = KV + 64 * LDT;   // V^T tile [d][key]

    const int tid  = threadIdx.x;
    const int wave = tid >> 6;
    const int lane = tid & 63;
    const int l15  = lane & 15;
    const int quad = lane >> 4;

    const int qt = blockIdx.x & 7;                // 8 q-tiles of 128
    const int h  = (blockIdx.x >> 3) % H_;
    const int b  = blockIdx.x / (8 * H_);
    const int q0 = qt * 128 + wave * 32;          // wave's first query row

    const ushort_t* qkB = qk + (size_t)b * N_ * C2;
    const ushort_t* vtB = vt + ((size_t)(b * H_ + h)) * D_ * N_;
    const int ho = h * D_;

    // Q fragments (B-operand now): col=l15 -> q, k=quad*8 (+32*kc)
    bf16x8 qf[2][2];
    #pragma unroll
    for (int rt = 0; rt < 2; ++rt)
        #pragma unroll
        for (int kc = 0; kc < 2; ++kc)
            qf[rt][kc] = *reinterpret_cast<const bf16x8*>(
                &qkB[(size_t)(q0 + rt * 16 + l15) * C2 + ho + kc * 32 + quad * 8]);

    // pad mask per C-layout output row (q = rt*16 + quad*4 + t), epilogue only
    int mrow[2][4];
    #pragma unroll
    for (int rt = 0; rt < 2; ++rt)
        #pragma unroll
        for (int t = 0; t < 4; ++t)
            mrow[rt][t] = pad_mask[b * N_ + q0 + rt * 16 + quad * 4 + t];

    f32x4 oacc[2][4] = {};
    float den[2] = {};                  // per-lane partial (this quad's keys)

    const int srow = tid >> 3;          // staging: 0..31
    const int scol = (tid & 7) * 8;     // 16B granule within 64-elem row

    // prologue: issue tile-0 loads
    uint4 kvr[2], vvr[2];
    #pragma unroll
    for (int hf = 0; hf < 2; ++hf) {
        const int r = srow + hf * 32;
        kvr[hf] = *reinterpret_cast<const uint4*>(
            &qkB[(size_t)r * C2 + C_ + ho + scol]);
        vvr[hf] = *reinterpret_cast<const uint4*>(&vtB[(size_t)r * N_ + scol]);
    }

    for (int k0 = 0; k0 < N_; k0 += 64) {
        __syncthreads();                 // prev tile's fragment reads done
        #pragma unroll
        for (int hf = 0; hf < 2; ++hf) {
            const int r = srow + hf * 32;
            *reinterpret_cast<uint4*>(&Ks [r * LDT + scol]) = kvr[hf];
            *reinterpret_cast<uint4*>(&Vts[r * LDT + scol]) = vvr[hf];
        }
        __syncthreads();
        // T14: issue NEXT tile's loads now; latency hides under QK/softmax/PV
        if (k0 + 64 < N_) {
            #pragma unroll
            for (int hf = 0; hf < 2; ++hf) {
                const int r = srow + hf * 32;
                kvr[hf] = *reinterpret_cast<const uint4*>(
                    &qkB[(size_t)(k0 + 64 + r) * C2 + C_ + ho + scol]);
                vvr[hf] = *reinterpret_cast<const uint4*>(
                    &vtB[(size_t)r * N_ + k0 + 64 + scol]);
            }
        }

        // S^T = K Q^T (swapped operands): lane holds
        // s[rt][ct][t] = S[key = ct*16+quad*4+t][q = rt*16+l15]
        f32x4 s[2][4] = {};
        #pragma unroll
        for (int kc = 0; kc < 2; ++kc) {
            bf16x8 kf[4];
            #pragma unroll
            for (int ct = 0; ct < 4; ++ct)
                kf[ct] = *reinterpret_cast<const bf16x8*>(
                    &Ks[(ct * 16 + l15) * LDT + kc * 32 + quad * 8]);
            #pragma unroll
            for (int rt = 0; rt < 2; ++rt)
                #pragma unroll
                for (int ct = 0; ct < 4; ++ct)
                    s[rt][ct] = __builtin_amdgcn_mfma_f32_16x16x32_bf16(
                        kf[ct], qf[rt][kc], s[rt][ct], 0, 0, 0);
        }

        // P = 2^S (Q pre-scaled by 0.125*log2 e); quantize round-half-up to
        // bf16 and pack pairs with EXPLICIT bit placement: T0 -> low half.
        unsigned pk[2][4][2];
        #pragma unroll
        for (int rt = 0; rt < 2; ++rt)
            #pragma unroll
            for (int ct = 0; ct < 4; ++ct) {
                const unsigned x0 = __float_as_uint(
                    __builtin_amdgcn_exp2f(s[rt][ct][0])) + 0x8000u;
                const unsigned x1 = __float_as_uint(
                    __builtin_amdgcn_exp2f(s[rt][ct][1])) + 0x8000u;
                const unsigned x2 = __float_as_uint(
                    __builtin_amdgcn_exp2f(s[rt][ct][2])) + 0x8000u;
                const unsigned x3 = __float_as_uint(
                    __builtin_amdgcn_exp2f(s[rt][ct][3])) + 0x8000u;
                const unsigned c0 = (x0 >> 16) | (x1 & 0xffff0000u);
                const unsigned c1 = (x2 >> 16) | (x3 & 0xffff0000u);
                // den sums the QUANTIZED P so the PV row still sums to 1
                den[rt] += __uint_as_float(c0 << 16)
                         + __uint_as_float(c0 & 0xffff0000u)
                         + __uint_as_float(c1 << 16)
                         + __uint_as_float(c1 & 0xffff0000u);
                pk[rt][ct][0] = c0;
                pk[rt][ct][1] = c1;
            }

        // O += P V, key-slot-permuted identically on A and B:
        //   slot quad*8+{0..3} <-> key kc*32+quad*4+{0..3}
        //   slot quad*8+{4..7} <-> key kc*32+16+quad*4+{0..3}
        #pragma unroll
        for (int kc = 0; kc < 2; ++kc) {
            bf16x8 pf[2];
            #pragma unroll
            for (int rt = 0; rt < 2; ++rt) {
                union { u32x4 u; bf16x8 b; } pu;
                pu.u = (u32x4){pk[rt][kc * 2][0], pk[rt][kc * 2][1],
                               pk[rt][kc * 2 + 1][0], pk[rt][kc * 2 + 1][1]};
                pf[rt] = pu.b;
            }
            #pragma unroll
            for (int dt = 0; dt < 4; ++dt) {
                union { u32x2 u2[2]; bf16x8 b; } vu;
                const ushort_t* vrow =
                    &Vts[(dt * 16 + l15) * LDT + kc * 32 + quad * 4];
                vu.u2[0] = *reinterpret_cast<const u32x2*>(vrow);
                vu.u2[1] = *reinterpret_cast<const u32x2*>(vrow + 16);
                const bf16x8 vf = vu.b;
                #pragma unroll
                for (int rt = 0; rt < 2; ++rt)
                    oacc[rt][dt] = __builtin_amdgcn_mfma_f32_16x16x32_bf16(
                        pf[rt], vf, oacc[rt][dt], 0, 0, 0);
            }
        }
    }

    // epilogue: reduce den across quads, normalize, stage O in freed LDS,
    // emit 16B stores.
    __syncthreads();                            // all waves done with Ks/Vts
    ushort_t* const scratch = KV + wave * 32 * LDT;   // wave-private 32 rows

    #pragma unroll
    for (int rt = 0; rt < 2; ++rt) {
        float v = den[rt];
        v += __shfl_xor(v, 16);
        v += __shfl_xor(v, 32);
        den[rt] = v;                  // full denom for q = rt*16+l15, all lanes
    }
    #pragma unroll
    for (int rt = 0; rt < 2; ++rt)
        #pragma unroll
        for (int t = 0; t < 4; ++t) {
            const float dv  = __shfl(den[rt], quad * 4 + t);
            const float inv = mrow[rt][t] ? 1.0f / dv : __builtin_nanf("");
            const int row = rt * 16 + quad * 4 + t;          // 0..31
            #pragma unroll
            for (int dt = 0; dt < 4; ++dt)
                scratch[row * LDT + dt * 16 + l15] = f2bf(oacc[rt][dt][t] * inv);
        }
    // wave-private: no __syncthreads needed; compiler orders via lgkmcnt
    {
        const int orow = lane >> 1;               // 0..31
        const int ocol = (lane & 1) * 32;         // 0 or 32
        const size_t gr = (size_t)(b * N_ + q0 + orow) * C_ + ho + ocol;
        #pragma unroll
        for (int i2 = 0; i2 < 4; ++i2) {
            uint4 w = *reinterpret_cast<const uint4*>(
                &scratch[orow * LDT + ocol + i2 * 8]);
            *reinterpret_cast<uint4*>(&y[gr + i2 * 8]) = w;
        }
    }
}

// ---------------------------------------------------------------------------
extern "C" void kernel_launch(void* const* d_in, const int* in_sizes, int n_in,
                              void* d_out, int out_size, void* d_ws, size_t ws_size,
                              hipStream_t stream)
{
    const float* x      = (const float*)d_in[0];
    const int*   pad    = (const int*)d_in[1];
    const float* w_attn = (const float*)d_in[2];
    const float* b_attn = (const float*)d_in[3];
    const float* w_proj = (const float*)d_in[4];
    const float* b_proj = (const float*)d_in[5];
    float* out = (float*)d_out;

    // ws (bf16 elems): qk [B*N,2C] | vt [B,H,D,N] | y(=xb) [B*N,C] | wat | wpt
    ushort_t* qkb = (ushort_t*)d_ws;
    ushort_t* vtb = qkb + (size_t)B_ * N_ * C2;
    ushort_t* y   = vtb + (size_t)B_ * H_ * D_ * N_;
    ushort_t* xb  = y;   // consumed by gemm1 before attn overwrites with y
    ushort_t* wat = y + (size_t)B_ * N_ * C_;
    ushort_t* wpt = wat + (size_t)C3 * C_;

    const int M = B_ * N_;

    // 0) conversions
    cvt_bf16<<<dim3((M * C_) / (256 * 4)), dim3(256), 0, stream>>>(x, xb, M * C_);
    transpose_to_bf16<<<dim3(C3 / 32, C_ / 32), dim3(256), 0, stream>>>(
        w_attn, wat, C_, C3);
    transpose_to_bf16<<<dim3(C_ / 32, C_ / 32), dim3(256), 0, stream>>>(
        w_proj, wpt, C_, C_);

    // 1) qkv projection: Q (pre-scaled 0.125*log2e), K -> qkb; V -> vtb transposed
    gemm_mfma<ushort_t, true><<<dim3(C3 / 128, M / 128), dim3(256), 0, stream>>>(
        xb, wat, b_attn, qkb, C2, vtb, M, C_, C3);

    // 2) attention -> y
    attn_mfma<<<dim3(B_ * H_ * 8), dim3(256), 0, stream>>>(qkb, vtb, pad, y);

    // 3) out = y @ w_proj + b_proj
    gemm_mfma<float, false><<<dim3(C_ / 128, M / 128), dim3(256), 0, stream>>>(
        y, wpt, b_proj, out, C_, nullptr, M, C_, C_);
}

// Round 4
// 198.943 us; speedup vs baseline: 1.1246x; 1.1246x over previous
//
#include <hip/hip_runtime.h>
#include <hip/hip_bf16.h>

// Problem constants (CausalSelfAttention_23768349016530)
#define B_  8
#define N_  1024
#define C_  768
#define H_  12
#define D_  64
#define C3  2304   // 3*C
#define C2  1536   // 2*C

typedef unsigned short ushort_t;
typedef __attribute__((ext_vector_type(8))) short bf16x8;   // 8 bf16 = 4 VGPR
typedef __attribute__((ext_vector_type(4))) float f32x4;    // MFMA 16x16 accumulator
typedef __attribute__((ext_vector_type(4))) unsigned int u32x4;
typedef __attribute__((ext_vector_type(2))) unsigned int u32x2;

__device__ __forceinline__ ushort_t f2bf(float f) {
    union { float f; unsigned int i; } v;
    v.f = f;
    unsigned int x = v.i;
    if ((x & 0x7f800000u) == 0x7f800000u && (x & 0x007fffffu))
        return (ushort_t)((x >> 16) | 0x0040u);   // quiet NaN
    return (ushort_t)((x + 0x7fffu + ((x >> 16) & 1u)) >> 16);  // RNE
}

__device__ __forceinline__ void st1(float* p, float v) { *p = v; }
__device__ __forceinline__ void st1(ushort_t* p, float v) { *p = f2bf(v); }

// ---------------------------------------------------------------------------
// fp32 -> bf16 elementwise (for x)
// ---------------------------------------------------------------------------
__global__ __launch_bounds__(256) void cvt_bf16(
    const float* __restrict__ X, ushort_t* __restrict__ Y, int n)
{
    int i = (blockIdx.x * 256 + threadIdx.x) * 4;
    if (i < n) {
        float4 f = *reinterpret_cast<const float4*>(X + i);
        ushort4 o;
        o.x = f2bf(f.x); o.y = f2bf(f.y); o.z = f2bf(f.z); o.w = f2bf(f.w);
        *reinterpret_cast<ushort4*>(Y + i) = o;
    }
}

// ---------------------------------------------------------------------------
// W[K][Nn] fp32  ->  WT[Nn][K] bf16   (32x32 LDS tile transpose)
// ---------------------------------------------------------------------------
__global__ __launch_bounds__(256) void transpose_to_bf16(
    const float* __restrict__ W, ushort_t* __restrict__ WT, int K, int Nn)
{
    __shared__ float t[32][33];
    const int n0 = blockIdx.x * 32, k0 = blockIdx.y * 32;
    const int tx = threadIdx.x & 31, ty = threadIdx.x >> 5;   // ty: 0..7
    #pragma unroll
    for (int i = 0; i < 4; ++i) {
        const int k = ty + i * 8;
        t[k][tx] = W[(size_t)(k0 + k) * Nn + n0 + tx];
    }
    __syncthreads();
    #pragma unroll
    for (int i = 0; i < 4; ++i) {
        const int n = ty + i * 8;
        WT[(size_t)(n0 + n) * K + k0 + tx] = f2bf(t[tx][n]);
    }
}

// ---------------------------------------------------------------------------
// MFMA GEMM: 128x128 tile, BK=64, 256 thr, XOR-swizzled LDS (conflict-free
// fragment reads; swizzle applied in the GLOBAL address so global_load_lds
// lane-linear dest still works: LDS slot s of row r holds k-granule s^(r&7)).
// SCALEQ folds 0.125*log2(e) into Q columns (attn then uses raw v_exp_f32,
// i.e. exp2, so softmax is unchanged mathematically). vtOut: V transposed.
// ---------------------------------------------------------------------------
#define GBK 64

__device__ __forceinline__ void gld_lds16(const ushort_t* g, ushort_t* lds) {
    __builtin_amdgcn_global_load_lds(
        (const __attribute__((address_space(1))) void*)g,
        (__attribute__((address_space(3))) void*)lds, 16, 0, 0);
}

template<typename TO, bool SCALEQ>
__global__ __launch_bounds__(256) void gemm_mfma(
    const ushort_t* __restrict__ A, const ushort_t* __restrict__ BT,
    const float* __restrict__ bias, TO* __restrict__ Y, int ldY,
    ushort_t* __restrict__ vtOut, int M, int K, int Nn)
{
    __shared__ ushort_t As[128 * GBK];   // [row][slot^], 128B rows
    __shared__ ushort_t Bs[128 * GBK];

    const int tid  = threadIdx.x;
    const int wave = tid >> 6;
    const int lane = tid & 63;
    const int row0 = blockIdx.y * 128;
    const int col0 = blockIdx.x * 128;
    const int wr   = (wave >> 1) * 64;
    const int wc   = (wave & 1) * 64;
    const int l15  = lane & 15;
    const int quad = lane >> 4;
    const int l7   = l15 & 7;

    // staging: lane -> (row = base + lane>>3, slot = lane&7); fetch granule
    // slot^row so that LDS slot s holds granule s^(r&7).
    const int srow = lane >> 3;                 // 0..7
    const int sg   = (lane & 7) ^ srow;         // data granule to fetch

    f32x4 acc[4][4] = {};

    for (int k0 = 0; k0 < K; k0 += GBK) {
        __syncthreads();
        #pragma unroll
        for (int it = 0; it < 4; ++it) {
            const int baseRow = wave * 32 + it * 8;           // wave-uniform
            const int r = baseRow + srow;
            gld_lds16(&A [(size_t)(row0 + r) * K + k0 + sg * 8], &As[baseRow * GBK]);
            gld_lds16(&BT[(size_t)(col0 + r) * K + k0 + sg * 8], &Bs[baseRow * GBK]);
        }
        __syncthreads();

        #pragma unroll
        for (int kc = 0; kc < 2; ++kc) {
            bf16x8 af[4], bf[4];
            #pragma unroll
            for (int i = 0; i < 4; ++i) {
                const int aslot = (kc * 4 + quad) ^ l7;
                af[i] = *reinterpret_cast<const bf16x8*>(
                    &As[(wr + i * 16 + l15) * GBK + aslot * 8]);
                bf[i] = *reinterpret_cast<const bf16x8*>(
                    &Bs[(wc + i * 16 + l15) * GBK + aslot * 8]);
            }
            #pragma unroll
            for (int i = 0; i < 4; ++i)
                #pragma unroll
                for (int j = 0; j < 4; ++j)
                    acc[i][j] = __builtin_amdgcn_mfma_f32_16x16x32_bf16(
                        af[i], bf[j], acc[i][j], 0, 0, 0);
        }
    }

    // per-wave-column-tile uniform Q-scale (columns < C_ are Q)
    // 0.125 * log2(e) so attention can use v_exp_f32 (base-2) directly.
    const float qs = (SCALEQ && (col0 + wc) < C_) ? 0.1803368801f : 1.0f;

    if (vtOut != nullptr && col0 >= C2) {
        // V part: write transposed vt[b][h][d][token]
        #pragma unroll
        for (int i = 0; i < 4; ++i) {
            const int r0 = row0 + wr + i * 16 + quad * 4;   // token base
            const int bb = r0 >> 10;
            const int n  = r0 & 1023;
            #pragma unroll
            for (int j = 0; j < 4; ++j) {
                const int c  = col0 + wc + j * 16 + l15;
                const int cv = c - C2;
                const int hh = cv >> 6, d = cv & 63;
                const float bv = bias[c];
                ushort4 o;
                o.x = f2bf(acc[i][j][0] + bv);
                o.y = f2bf(acc[i][j][1] + bv);
                o.z = f2bf(acc[i][j][2] + bv);
                o.w = f2bf(acc[i][j][3] + bv);
                *reinterpret_cast<ushort4*>(
                    &vtOut[((size_t)(bb * H_ + hh) * D_ + d) * N_ + n]) = o;
            }
        }
    } else {
        #pragma unroll
        for (int i = 0; i < 4; ++i) {
            const int r = row0 + wr + i * 16 + quad * 4;
            #pragma unroll
            for (int j = 0; j < 4; ++j) {
                const int c = col0 + wc + j * 16 + l15;
                const float bv = bias[c];
                #pragma unroll
                for (int t = 0; t < 4; ++t)
                    st1(&Y[(size_t)(r + t) * ldY + c], (acc[i][j][t] + bv) * qs);
            }
        }
    }
}

// ---------------------------------------------------------------------------
// MFMA attention, v4:
//  * v3 regression root-caused: +121MB HBM WRITE_SIZE = scratch traffic from
//    stack-allocated vector unions in the PV inner loop + T14 prefetch regs.
//    v4 removes both: all vector repacks are __builtin_shufflevector /
//    __builtin_bit_cast (pure SSA), and staging goes through
//    global_load_lds (no staging VGPRs at all), same as the GEMM.
//  * LDS rows are lane-linear stride-64 (global_load_lds requirement); the
//    GEMM's XOR swizzle is applied in the GLOBAL source address: LDS slot s
//    of row r holds granule s^(r&7). Reads use slot = g^(r&7) -> worst case
//    2-way bank aliasing (free).
//  * swapped QK^T (mfma(K,Q)): lane holds P for its own query column; P is
//    quantized+packed in-register (explicit round-half-up bit-pack, T0->lo),
//    PV consumes it directly under a key-slot permutation applied equally to
//    the V fragment. No P LDS round-trip. LDS total 16KB.
//  * Q pre-scaled by 0.125*log2(e) -> softmax numerator is one v_exp_f32.
//  * den sums the QUANTIZED P so each softmax row sums to exactly 1.
//  * T5: s_setprio(1) around MFMA bursts.
// ---------------------------------------------------------------------------
__global__ __launch_bounds__(256) void attn_mfma(
    const ushort_t* __restrict__ qk, const ushort_t* __restrict__ vt,
    const int* __restrict__ pad_mask, ushort_t* __restrict__ y)
{
    __shared__ __align__(16) ushort_t KV[2 * 64 * 64];   // 16 KB
    ushort_t* const Ks  = KV;              // K tile  [key][d], stride 64
    ushort_t* const Vts = KV + 64 * 64;    // V^T tile [d][key], stride 64

    const int tid  = threadIdx.x;
    const int wave = tid >> 6;
    const int lane = tid & 63;
    const int l15  = lane & 15;
    const int quad = lane >> 4;
    const int l7   = l15 & 7;

    const int qt = blockIdx.x & 7;                // 8 q-tiles of 128
    const int h  = (blockIdx.x >> 3) % H_;
    const int b  = blockIdx.x / (8 * H_);
    const int q0 = qt * 128 + wave * 32;          // wave's first query row

    const ushort_t* qkB = qk + (size_t)b * N_ * C2;
    const ushort_t* vtB = vt + ((size_t)(b * H_ + h)) * D_ * N_;
    const int ho = h * D_;

    // Q fragments (B-operand): col=l15 -> q, k=quad*8 (+32*kc)
    bf16x8 qf[2][2];
    #pragma unroll
    for (int rt = 0; rt < 2; ++rt)
        #pragma unroll
        for (int kc = 0; kc < 2; ++kc)
            qf[rt][kc] = *reinterpret_cast<const bf16x8*>(
                &qkB[(size_t)(q0 + rt * 16 + l15) * C2 + ho + kc * 32 + quad * 8]);

    // pad mask per C-layout output row (q = rt*16 + quad*4 + t), epilogue only
    int mrow[2][4];
    #pragma unroll
    for (int rt = 0; rt < 2; ++rt)
        #pragma unroll
        for (int t = 0; t < 4; ++t)
            mrow[rt][t] = pad_mask[b * N_ + q0 + rt * 16 + quad * 4 + t];

    f32x4 oacc[2][4] = {};
    float den[2] = {};                  // per-lane partial (this quad's keys)

    // staging: per wave, rows wave*16 .. wave*16+15 of both K and Vt tiles.
    const int srow = lane >> 3;            // 0..7 within an 8-row group
    const int sg   = (lane & 7) ^ srow;    // swizzled source granule (16B)

    for (int k0 = 0; k0 < N_; k0 += 64) {
        __syncthreads();                   // prev tile fully consumed
        #pragma unroll
        for (int it = 0; it < 2; ++it) {
            const int base = wave * 16 + it * 8;          // wave-uniform
            const int r = base + srow;
            gld_lds16(&qkB[(size_t)(k0 + r) * C2 + C_ + ho + sg * 8],
                      &Ks[base * 64]);
            gld_lds16(&vtB[(size_t)r * N_ + k0 + sg * 8],
                      &Vts[base * 64]);
        }
        __syncthreads();                   // vmcnt(0) drain + barrier

        // S^T = K Q^T (swapped operands): lane holds
        // s[rt][ct][t] = S[key = ct*16+quad*4+t][q = rt*16+l15]
        f32x4 s[2][4] = {};
        #pragma unroll
        for (int kc = 0; kc < 2; ++kc) {
            bf16x8 kf[4];
            #pragma unroll
            for (int ct = 0; ct < 4; ++ct) {
                const int slot = (kc * 4 + quad) ^ l7;
                kf[ct] = *reinterpret_cast<const bf16x8*>(
                    &Ks[(ct * 16 + l15) * 64 + slot * 8]);
            }
            __builtin_amdgcn_s_setprio(1);
            #pragma unroll
            for (int rt = 0; rt < 2; ++rt)
                #pragma unroll
                for (int ct = 0; ct < 4; ++ct)
                    s[rt][ct] = __builtin_amdgcn_mfma_f32_16x16x32_bf16(
                        kf[ct], qf[rt][kc], s[rt][ct], 0, 0, 0);
            __builtin_amdgcn_s_setprio(0);
        }

        // P = 2^S (Q pre-scaled by 0.125*log2 e); quantize round-half-up to
        // bf16 and pack pairs with EXPLICIT bit placement: T0 -> low half.
        unsigned pk[2][4][2];
        #pragma unroll
        for (int rt = 0; rt < 2; ++rt)
            #pragma unroll
            for (int ct = 0; ct < 4; ++ct) {
                const unsigned x0 = __float_as_uint(
                    __builtin_amdgcn_exp2f(s[rt][ct][0])) + 0x8000u;
                const unsigned x1 = __float_as_uint(
                    __builtin_amdgcn_exp2f(s[rt][ct][1])) + 0x8000u;
                const unsigned x2 = __float_as_uint(
                    __builtin_amdgcn_exp2f(s[rt][ct][2])) + 0x8000u;
                const unsigned x3 = __float_as_uint(
                    __builtin_amdgcn_exp2f(s[rt][ct][3])) + 0x8000u;
                const unsigned c0 = (x0 >> 16) | (x1 & 0xffff0000u);
                const unsigned c1 = (x2 >> 16) | (x3 & 0xffff0000u);
                // den sums the QUANTIZED P so the PV row still sums to 1
                den[rt] += __uint_as_float(c0 << 16)
                         + __uint_as_float(c0 & 0xffff0000u)
                         + __uint_as_float(c1 << 16)
                         + __uint_as_float(c1 & 0xffff0000u);
                pk[rt][ct][0] = c0;
                pk[rt][ct][1] = c1;
            }

        // O += P V, key-slot-permuted identically on A and B:
        //   slot quad*8+{0..3} <-> key kc*32+quad*4+{0..3}
        //   slot quad*8+{4..7} <-> key kc*32+16+quad*4+{0..3}
        #pragma unroll
        for (int kc = 0; kc < 2; ++kc) {
            bf16x8 pf[2], vf[4];
            #pragma unroll
            for (int rt = 0; rt < 2; ++rt) {
                const u32x4 pw = (u32x4){pk[rt][kc * 2][0], pk[rt][kc * 2][1],
                                         pk[rt][kc * 2 + 1][0],
                                         pk[rt][kc * 2 + 1][1]};
                pf[rt] = __builtin_bit_cast(bf16x8, pw);
            }
            #pragma unroll
            for (int dt = 0; dt < 4; ++dt) {
                const int d  = dt * 16 + l15;
                const int g1 = kc * 4 + (quad >> 1);
                const int o  = (quad & 1) * 4;     // elements within granule
                const u32x2 va = *reinterpret_cast<const u32x2*>(
                    &Vts[d * 64 + ((g1 ^ l7)) * 8 + o]);
                const u32x2 vb = *reinterpret_cast<const u32x2*>(
                    &Vts[d * 64 + (((g1 + 2) ^ l7)) * 8 + o]);
                const u32x4 wv = __builtin_shufflevector(va, vb, 0, 1, 2, 3);
                vf[dt] = __builtin_bit_cast(bf16x8, wv);
            }
            __builtin_amdgcn_s_setprio(1);
            #pragma unroll
            for (int rt = 0; rt < 2; ++rt)
                #pragma unroll
                for (int dt = 0; dt < 4; ++dt)
                    oacc[rt][dt] = __builtin_amdgcn_mfma_f32_16x16x32_bf16(
                        pf[rt], vf[dt], oacc[rt][dt], 0, 0, 0);
            __builtin_amdgcn_s_setprio(0);
        }
    }

    // epilogue: reduce den across quads, normalize, stage O in freed LDS
    // (XOR-swizzled rows, stride 64), emit 16B stores.
    __syncthreads();                            // all waves done with Ks/Vts
    ushort_t* const scratch = KV + wave * 32 * 64;   // wave-private 32 rows

    #pragma unroll
    for (int rt = 0; rt < 2; ++rt) {
        float v = den[rt];
        v += __shfl_xor(v, 16);
        v += __shfl_xor(v, 32);
        den[rt] = v;                  // full denom for q = rt*16+l15, all lanes
    }
    #pragma unroll
    for (int rt = 0; rt < 2; ++rt)
        #pragma unroll
        for (int t = 0; t < 4; ++t) {
            const float dv  = __shfl(den[rt], quad * 4 + t);
            const float inv = mrow[rt][t] ? 1.0f / dv : __builtin_nanf("");
            const int row = rt * 16 + quad * 4 + t;          // 0..31
            #pragma unroll
            for (int dt = 0; dt < 4; ++dt) {
                const int slot = (dt * 2 + (l15 >> 3)) ^ (row & 7);
                scratch[row * 64 + slot * 8 + l7] =
                    f2bf(oacc[rt][dt][t] * inv);
            }
        }
    // wave-private: no __syncthreads needed; compiler orders via lgkmcnt
    {
        const int orow = lane >> 1;               // 0..31
        const int og   = (lane & 1) * 4;          // granule base: 0 or 4
        const size_t gr = (size_t)(b * N_ + q0 + orow) * C_ + ho;
        #pragma unroll
        for (int i2 = 0; i2 < 4; ++i2) {
            const int g = og + i2;
            uint4 w = *reinterpret_cast<const uint4*>(
                &scratch[orow * 64 + (g ^ (orow & 7)) * 8]);
            *reinterpret_cast<uint4*>(&y[gr + g * 8]) = w;
        }
    }
}

// ---------------------------------------------------------------------------
extern "C" void kernel_launch(void* const* d_in, const int* in_sizes, int n_in,
                              void* d_out, int out_size, void* d_ws, size_t ws_size,
                              hipStream_t stream)
{
    const float* x      = (const float*)d_in[0];
    const int*   pad    = (const int*)d_in[1];
    const float* w_attn = (const float*)d_in[2];
    const float* b_attn = (const float*)d_in[3];
    const float* w_proj = (const float*)d_in[4];
    const float* b_proj = (const float*)d_in[5];
    float* out = (float*)d_out;

    // ws (bf16 elems): qk [B*N,2C] | vt [B,H,D,N] | y(=xb) [B*N,C] | wat | wpt
    ushort_t* qkb = (ushort_t*)d_ws;
    ushort_t* vtb = qkb + (size_t)B_ * N_ * C2;
    ushort_t* y   = vtb + (size_t)B_ * H_ * D_ * N_;
    ushort_t* xb  = y;   // consumed by gemm1 before attn overwrites with y
    ushort_t* wat = y + (size_t)B_ * N_ * C_;
    ushort_t* wpt = wat + (size_t)C3 * C_;

    const int M = B_ * N_;

    // 0) conversions
    cvt_bf16<<<dim3((M * C_) / (256 * 4)), dim3(256), 0, stream>>>(x, xb, M * C_);
    transpose_to_bf16<<<dim3(C3 / 32, C_ / 32), dim3(256), 0, stream>>>(
        w_attn, wat, C_, C3);
    transpose_to_bf16<<<dim3(C_ / 32, C_ / 32), dim3(256), 0, stream>>>(
        w_proj, wpt, C_, C_);

    // 1) qkv projection: Q (pre-scaled 0.125*log2e), K -> qkb; V -> vtb transposed
    gemm_mfma<ushort_t, true><<<dim3(C3 / 128, M / 128), dim3(256), 0, stream>>>(
        xb, wat, b_attn, qkb, C2, vtb, M, C_, C3);

    // 2) attention -> y
    attn_mfma<<<dim3(B_ * H_ * 8), dim3(256), 0, stream>>>(qkb, vtb, pad, y);

    // 3) out = y @ w_proj + b_proj
    gemm_mfma<float, false><<<dim3(C_ / 128, M / 128), dim3(256), 0, stream>>>(
        y, wpt, b_proj, out, C_, nullptr, M, C_, C_);
}

// Round 6
// 192.903 us; speedup vs baseline: 1.1599x; 1.0313x over previous
//
#include <hip/hip_runtime.h>
#include <hip/hip_bf16.h>

// Problem constants (CausalSelfAttention_23768349016530)
#define B_  8
#define N_  1024
#define C_  768
#define H_  12
#define D_  64
#define C3  2304   // 3*C
#define C2  1536   // 2*C

typedef unsigned short ushort_t;
typedef __attribute__((ext_vector_type(8))) short bf16x8;   // 8 bf16 = 4 VGPR
typedef __attribute__((ext_vector_type(4))) float f32x4;    // MFMA 16x16 accumulator
typedef __attribute__((ext_vector_type(4))) unsigned int u32x4;
typedef __attribute__((ext_vector_type(2))) unsigned int u32x2;

__device__ __forceinline__ ushort_t f2bf(float f) {
    union { float f; unsigned int i; } v;
    v.f = f;
    unsigned int x = v.i;
    if ((x & 0x7f800000u) == 0x7f800000u && (x & 0x007fffffu))
        return (ushort_t)((x >> 16) | 0x0040u);   // quiet NaN
    return (ushort_t)((x + 0x7fffu + ((x >> 16) & 1u)) >> 16);  // RNE
}

__device__ __forceinline__ void st1(float* p, float v) { *p = v; }
__device__ __forceinline__ void st1(ushort_t* p, float v) { *p = f2bf(v); }

// ---------------------------------------------------------------------------
// Merged prep kernel: fp32->bf16 convert of x, plus both weight transposes.
// One launch instead of three. Block ranges:
// [0, NCVT) cvt | [NCVT, NCVT+NTA) w_attn | rest w_proj.
// ---------------------------------------------------------------------------
#define NCVT 6144            // (B*N*C) / (256*4)
#define NTA  1728            // (C3/32)*(C/32)
#define NTP  576             // (C/32)*(C/32)

__device__ __forceinline__ void transpose_tile(
    const float* __restrict__ W, ushort_t* __restrict__ WT,
    int K, int Nn, int n0, int k0, float (*t)[33], int tid)
{
    const int tx = tid & 31, ty = tid >> 5;   // ty: 0..7
    #pragma unroll
    for (int i = 0; i < 4; ++i) {
        const int k = ty + i * 8;
        t[k][tx] = W[(size_t)(k0 + k) * Nn + n0 + tx];
    }
    __syncthreads();
    #pragma unroll
    for (int i = 0; i < 4; ++i) {
        const int n = ty + i * 8;
        WT[(size_t)(n0 + n) * K + k0 + tx] = f2bf(t[tx][n]);
    }
}

__global__ __launch_bounds__(256) void prep(
    const float* __restrict__ X, ushort_t* __restrict__ Y,
    const float* __restrict__ Wa, ushort_t* __restrict__ WaT,
    const float* __restrict__ Wp, ushort_t* __restrict__ WpT)
{
    __shared__ float t[32][33];
    const int bid = blockIdx.x;
    const int tid = threadIdx.x;
    if (bid < NCVT) {
        const int i = (bid * 256 + tid) * 4;
        float4 f = *reinterpret_cast<const float4*>(X + i);
        ushort4 o;
        o.x = f2bf(f.x); o.y = f2bf(f.y); o.z = f2bf(f.z); o.w = f2bf(f.w);
        *reinterpret_cast<ushort4*>(Y + i) = o;
    } else if (bid < NCVT + NTA) {
        const int tt = bid - NCVT;
        transpose_tile(Wa, WaT, C_, C3, (tt % (C3 / 32)) * 32,
                       (tt / (C3 / 32)) * 32, t, tid);
    } else {
        const int tt = bid - NCVT - NTA;
        transpose_tile(Wp, WpT, C_, C_, (tt % (C_ / 32)) * 32,
                       (tt / (C_ / 32)) * 32, t, tid);
    }
}

// ---------------------------------------------------------------------------
// MFMA GEMM: 128x128 tile, BK=64, 256 thr, XOR-swizzled LDS (conflict-free
// fragment reads; swizzle applied in the GLOBAL address so global_load_lds
// lane-linear dest still works: LDS slot s of row r holds k-granule s^(r&7)).
// SCALEQ folds 0.125*log2(e) into Q columns (attn then uses raw v_exp_f32,
// i.e. exp2, so softmax is unchanged mathematically). vtOut: V transposed.
// T1: bijective chunked XCD swizzle: each XCD-L2 gets a contiguous run of
// row-panels (8 A-panels + full B ~ L2-resident), so the per-K-step vmcnt(0)
// drains hit L2 (~200cy) instead of HBM (~900cy).
// ---------------------------------------------------------------------------
#define GBK 64

__device__ __forceinline__ void gld_lds16(const ushort_t* g, ushort_t* lds) {
    __builtin_amdgcn_global_load_lds(
        (const __attribute__((address_space(1))) void*)g,
        (__attribute__((address_space(3))) void*)lds, 16, 0, 0);
}

template<typename TO, bool SCALEQ>
__global__ __launch_bounds__(256) void gemm_mfma(
    const ushort_t* __restrict__ A, const ushort_t* __restrict__ BT,
    const float* __restrict__ bias, TO* __restrict__ Y, int ldY,
    ushort_t* __restrict__ vtOut, int M, int K, int Nn)
{
    __shared__ ushort_t As[128 * GBK];   // [row][slot^], 128B rows
    __shared__ ushort_t Bs[128 * GBK];

    const int tid  = threadIdx.x;
    const int wave = tid >> 6;
    const int lane = tid & 63;

    // XCD swizzle: hw block i runs on XCD i%8; give XCD k the contiguous
    // work-ids [k*chunk, (k+1)*chunk). Row-major work decode (nbx cols).
    const int nbx  = Nn / 128;
    const int nblk = nbx * (M / 128);
    const int hwid = blockIdx.y * gridDim.x + blockIdx.x;
    const int wid  = (hwid & 7) * (nblk >> 3) + (hwid >> 3);
    const int row0 = (wid / nbx) * 128;
    const int col0 = (wid % nbx) * 128;

    const int wr   = (wave >> 1) * 64;
    const int wc   = (wave & 1) * 64;
    const int l15  = lane & 15;
    const int quad = lane >> 4;
    const int l7   = l15 & 7;

    // staging: lane -> (row = base + lane>>3, slot = lane&7); fetch granule
    // slot^row so that LDS slot s holds granule s^(r&7).
    const int srow = lane >> 3;                 // 0..7
    const int sg   = (lane & 7) ^ srow;         // data granule to fetch

    f32x4 acc[4][4] = {};

    for (int k0 = 0; k0 < K; k0 += GBK) {
        __syncthreads();
        #pragma unroll
        for (int it = 0; it < 4; ++it) {
            const int baseRow = wave * 32 + it * 8;           // wave-uniform
            const int r = baseRow + srow;
            gld_lds16(&A [(size_t)(row0 + r) * K + k0 + sg * 8], &As[baseRow * GBK]);
            gld_lds16(&BT[(size_t)(col0 + r) * K + k0 + sg * 8], &Bs[baseRow * GBK]);
        }
        __syncthreads();

        #pragma unroll
        for (int kc = 0; kc < 2; ++kc) {
            bf16x8 af[4], bf[4];
            #pragma unroll
            for (int i = 0; i < 4; ++i) {
                const int aslot = (kc * 4 + quad) ^ l7;
                af[i] = *reinterpret_cast<const bf16x8*>(
                    &As[(wr + i * 16 + l15) * GBK + aslot * 8]);
                bf[i] = *reinterpret_cast<const bf16x8*>(
                    &Bs[(wc + i * 16 + l15) * GBK + aslot * 8]);
            }
            #pragma unroll
            for (int i = 0; i < 4; ++i)
                #pragma unroll
                for (int j = 0; j < 4; ++j)
                    acc[i][j] = __builtin_amdgcn_mfma_f32_16x16x32_bf16(
                        af[i], bf[j], acc[i][j], 0, 0, 0);
        }
    }

    // per-wave-column-tile uniform Q-scale (columns < C_ are Q)
    // 0.125 * log2(e) so attention can use v_exp_f32 (base-2) directly.
    const float qs = (SCALEQ && (col0 + wc) < C_) ? 0.1803368801f : 1.0f;

    if (vtOut != nullptr && col0 >= C2) {
        // V part: write transposed vt[b][h][d][token]
        #pragma unroll
        for (int i = 0; i < 4; ++i) {
            const int r0 = row0 + wr + i * 16 + quad * 4;   // token base
            const int bb = r0 >> 10;
            const int n  = r0 & 1023;
            #pragma unroll
            for (int j = 0; j < 4; ++j) {
                const int c  = col0 + wc + j * 16 + l15;
                const int cv = c - C2;
                const int hh = cv >> 6, d = cv & 63;
                const float bv = bias[c];
                ushort4 o;
                o.x = f2bf(acc[i][j][0] + bv);
                o.y = f2bf(acc[i][j][1] + bv);
                o.z = f2bf(acc[i][j][2] + bv);
                o.w = f2bf(acc[i][j][3] + bv);
                *reinterpret_cast<ushort4*>(
                    &vtOut[((size_t)(bb * H_ + hh) * D_ + d) * N_ + n]) = o;
            }
        }
    } else {
        #pragma unroll
        for (int i = 0; i < 4; ++i) {
            const int r = row0 + wr + i * 16 + quad * 4;
            #pragma unroll
            for (int j = 0; j < 4; ++j) {
                const int c = col0 + wc + j * 16 + l15;
                const float bv = bias[c];
                #pragma unroll
                for (int t = 0; t < 4; ++t)
                    st1(&Y[(size_t)(r + t) * ldY + c], (acc[i][j][t] + bv) * qs);
            }
        }
    }
}

// ---------------------------------------------------------------------------
// MFMA attention, v6 (= v5 + epilogue hardening):
//  * staging via global_load_lds, lane-linear LDS, XOR swizzle in the global
//    source address (slot s of row r holds granule s^(r&7)); reads use
//    slot = g^(r&7) -> worst 2-way aliasing (free). No staging VGPRs.
//  * swapped QK^T (mfma(K,Q)): lane holds P for its own query column; P is
//    quantized+packed in-register (explicit round-half-up bit-pack, T0->lo),
//    PV consumes it directly under a key-slot permutation applied equally to
//    the V fragment. No P LDS round-trip. LDS total 16KB.
//  * Q pre-scaled by 0.125*log2(e) -> softmax numerator is one v_exp_f32.
//  * den sums the QUANTIZED P so each softmax row sums to exactly 1.
//  * T5: s_setprio(1) around MFMA bursts (attn-positive per catalog).
//  * T1: chunked XCD swizzle (768 = 8*96): XCD k owns batch k.
//  * v6: __syncthreads() between the epilogue's scalar scratch writes and
//    the cross-typed uint4 re-reads. The previous implicit (in-wave lgkmcnt)
//    ordering relied on the compiler not reordering across a type-punned
//    LDS alias; the barrier makes it architectural. Suspected cause of the
//    v5 post-timing divergence (warm-replay-only scheduling window).
// ---------------------------------------------------------------------------
__global__ __launch_bounds__(256) void attn_mfma(
    const ushort_t* __restrict__ qk, const ushort_t* __restrict__ vt,
    const int* __restrict__ pad_mask, ushort_t* __restrict__ y)
{
    __shared__ __align__(16) ushort_t KV[2 * 64 * 64];   // 16 KB
    ushort_t* const Ks  = KV;              // K tile  [key][d], stride 64
    ushort_t* const Vts = KV + 64 * 64;    // V^T tile [d][key], stride 64

    const int tid  = threadIdx.x;
    const int wave = tid >> 6;
    const int lane = tid & 63;
    const int l15  = lane & 15;
    const int quad = lane >> 4;
    const int l7   = l15 & 7;

    // XCD swizzle: 768 blocks = 8 XCDs * 96; work-id chunk of 96 = one batch.
    const int wid = (blockIdx.x & 7) * 96 + (blockIdx.x >> 3);
    const int qt = wid & 7;                       // 8 q-tiles of 128
    const int hb = wid >> 3;
    const int h  = hb % H_;
    const int b  = hb / H_;
    const int q0 = qt * 128 + wave * 32;          // wave's first query row

    const ushort_t* qkB = qk + (size_t)b * N_ * C2;
    const ushort_t* vtB = vt + ((size_t)(b * H_ + h)) * D_ * N_;
    const int ho = h * D_;

    // Q fragments (B-operand): col=l15 -> q, k=quad*8 (+32*kc)
    bf16x8 qf[2][2];
    #pragma unroll
    for (int rt = 0; rt < 2; ++rt)
        #pragma unroll
        for (int kc = 0; kc < 2; ++kc)
            qf[rt][kc] = *reinterpret_cast<const bf16x8*>(
                &qkB[(size_t)(q0 + rt * 16 + l15) * C2 + ho + kc * 32 + quad * 8]);

    // pad mask per C-layout output row (q = rt*16 + quad*4 + t), epilogue only
    int mrow[2][4];
    #pragma unroll
    for (int rt = 0; rt < 2; ++rt)
        #pragma unroll
        for (int t = 0; t < 4; ++t)
            mrow[rt][t] = pad_mask[b * N_ + q0 + rt * 16 + quad * 4 + t];

    f32x4 oacc[2][4] = {};
    float den[2] = {};                  // per-lane partial (this quad's keys)

    // staging: per wave, rows wave*16 .. wave*16+15 of both K and Vt tiles.
    const int srow = lane >> 3;            // 0..7 within an 8-row group
    const int sg   = (lane & 7) ^ srow;    // swizzled source granule (16B)

    for (int k0 = 0; k0 < N_; k0 += 64) {
        __syncthreads();                   // prev tile fully consumed
        #pragma unroll
        for (int it = 0; it < 2; ++it) {
            const int base = wave * 16 + it * 8;          // wave-uniform
            const int r = base + srow;
            gld_lds16(&qkB[(size_t)(k0 + r) * C2 + C_ + ho + sg * 8],
                      &Ks[base * 64]);
            gld_lds16(&vtB[(size_t)r * N_ + k0 + sg * 8],
                      &Vts[base * 64]);
        }
        __syncthreads();                   // vmcnt(0) drain + barrier

        // S^T = K Q^T (swapped operands): lane holds
        // s[rt][ct][t] = S[key = ct*16+quad*4+t][q = rt*16+l15]
        f32x4 s[2][4] = {};
        #pragma unroll
        for (int kc = 0; kc < 2; ++kc) {
            bf16x8 kf[4];
            #pragma unroll
            for (int ct = 0; ct < 4; ++ct) {
                const int slot = (kc * 4 + quad) ^ l7;
                kf[ct] = *reinterpret_cast<const bf16x8*>(
                    &Ks[(ct * 16 + l15) * 64 + slot * 8]);
            }
            __builtin_amdgcn_s_setprio(1);
            #pragma unroll
            for (int rt = 0; rt < 2; ++rt)
                #pragma unroll
                for (int ct = 0; ct < 4; ++ct)
                    s[rt][ct] = __builtin_amdgcn_mfma_f32_16x16x32_bf16(
                        kf[ct], qf[rt][kc], s[rt][ct], 0, 0, 0);
            __builtin_amdgcn_s_setprio(0);
        }

        // P = 2^S (Q pre-scaled by 0.125*log2 e); quantize round-half-up to
        // bf16 and pack pairs with EXPLICIT bit placement: T0 -> low half.
        unsigned pk[2][4][2];
        #pragma unroll
        for (int rt = 0; rt < 2; ++rt)
            #pragma unroll
            for (int ct = 0; ct < 4; ++ct) {
                const unsigned x0 = __float_as_uint(
                    __builtin_amdgcn_exp2f(s[rt][ct][0])) + 0x8000u;
                const unsigned x1 = __float_as_uint(
                    __builtin_amdgcn_exp2f(s[rt][ct][1])) + 0x8000u;
                const unsigned x2 = __float_as_uint(
                    __builtin_amdgcn_exp2f(s[rt][ct][2])) + 0x8000u;
                const unsigned x3 = __float_as_uint(
                    __builtin_amdgcn_exp2f(s[rt][ct][3])) + 0x8000u;
                const unsigned c0 = (x0 >> 16) | (x1 & 0xffff0000u);
                const unsigned c1 = (x2 >> 16) | (x3 & 0xffff0000u);
                // den sums the QUANTIZED P so the PV row still sums to 1
                den[rt] += __uint_as_float(c0 << 16)
                         + __uint_as_float(c0 & 0xffff0000u)
                         + __uint_as_float(c1 << 16)
                         + __uint_as_float(c1 & 0xffff0000u);
                pk[rt][ct][0] = c0;
                pk[rt][ct][1] = c1;
            }

        // O += P V, key-slot-permuted identically on A and B:
        //   slot quad*8+{0..3} <-> key kc*32+quad*4+{0..3}
        //   slot quad*8+{4..7} <-> key kc*32+16+quad*4+{0..3}
        #pragma unroll
        for (int kc = 0; kc < 2; ++kc) {
            bf16x8 pf[2], vf[4];
            #pragma unroll
            for (int rt = 0; rt < 2; ++rt) {
                const u32x4 pw = (u32x4){pk[rt][kc * 2][0], pk[rt][kc * 2][1],
                                         pk[rt][kc * 2 + 1][0],
                                         pk[rt][kc * 2 + 1][1]};
                pf[rt] = __builtin_bit_cast(bf16x8, pw);
            }
            #pragma unroll
            for (int dt = 0; dt < 4; ++dt) {
                const int d  = dt * 16 + l15;
                const int g1 = kc * 4 + (quad >> 1);
                const int o  = (quad & 1) * 4;     // elements within granule
                const u32x2 va = *reinterpret_cast<const u32x2*>(
                    &Vts[d * 64 + ((g1 ^ l7)) * 8 + o]);
                const u32x2 vb = *reinterpret_cast<const u32x2*>(
                    &Vts[d * 64 + (((g1 + 2) ^ l7)) * 8 + o]);
                const u32x4 wv = __builtin_shufflevector(va, vb, 0, 1, 2, 3);
                vf[dt] = __builtin_bit_cast(bf16x8, wv);
            }
            __builtin_amdgcn_s_setprio(1);
            #pragma unroll
            for (int rt = 0; rt < 2; ++rt)
                #pragma unroll
                for (int dt = 0; dt < 4; ++dt)
                    oacc[rt][dt] = __builtin_amdgcn_mfma_f32_16x16x32_bf16(
                        pf[rt], vf[dt], oacc[rt][dt], 0, 0, 0);
            __builtin_amdgcn_s_setprio(0);
        }
    }

    // epilogue: reduce den across quads, normalize, stage O in freed LDS
    // (XOR-swizzled rows, stride 64), emit 16B stores.
    __syncthreads();                            // all waves done with Ks/Vts
    ushort_t* const scratch = KV + wave * 32 * 64;   // wave-private 32 rows

    #pragma unroll
    for (int rt = 0; rt < 2; ++rt) {
        float v = den[rt];
        v += __shfl_xor(v, 16);
        v += __shfl_xor(v, 32);
        den[rt] = v;                  // full denom for q = rt*16+l15, all lanes
    }
    #pragma unroll
    for (int rt = 0; rt < 2; ++rt)
        #pragma unroll
        for (int t = 0; t < 4; ++t) {
            const float dv  = __shfl(den[rt], quad * 4 + t);
            const float inv = mrow[rt][t] ? 1.0f / dv : __builtin_nanf("");
            const int row = rt * 16 + quad * 4 + t;          // 0..31
            #pragma unroll
            for (int dt = 0; dt < 4; ++dt) {
                const int slot = (dt * 2 + (l15 >> 3)) ^ (row & 7);
                scratch[row * 64 + slot * 8 + l7] =
                    f2bf(oacc[rt][dt][t] * inv);
            }
        }
    // v6 hardening: architectural fence between the scalar scratch writes
    // and the cross-typed vector re-reads (was implicit in-wave ordering).
    __syncthreads();
    {
        const int orow = lane >> 1;               // 0..31
        const int og   = (lane & 1) * 4;          // granule base: 0 or 4
        const size_t gr = (size_t)(b * N_ + q0 + orow) * C_ + ho;
        #pragma unroll
        for (int i2 = 0; i2 < 4; ++i2) {
            const int g = og + i2;
            uint4 w = *reinterpret_cast<const uint4*>(
                &scratch[orow * 64 + (g ^ (orow & 7)) * 8]);
            *reinterpret_cast<uint4*>(&y[gr + g * 8]) = w;
        }
    }
}

// ---------------------------------------------------------------------------
extern "C" void kernel_launch(void* const* d_in, const int* in_sizes, int n_in,
                              void* d_out, int out_size, void* d_ws, size_t ws_size,
                              hipStream_t stream)
{
    const float* x      = (const float*)d_in[0];
    const int*   pad    = (const int*)d_in[1];
    const float* w_attn = (const float*)d_in[2];
    const float* b_attn = (const float*)d_in[3];
    const float* w_proj = (const float*)d_in[4];
    const float* b_proj = (const float*)d_in[5];
    float* out = (float*)d_out;

    // ws (bf16 elems): qk [B*N,2C] | vt [B,H,D,N] | y(=xb) [B*N,C] | wat | wpt
    ushort_t* qkb = (ushort_t*)d_ws;
    ushort_t* vtb = qkb + (size_t)B_ * N_ * C2;
    ushort_t* y   = vtb + (size_t)B_ * H_ * D_ * N_;
    ushort_t* xb  = y;   // consumed by gemm1 before attn overwrites with y
    ushort_t* wat = y + (size_t)B_ * N_ * C_;
    ushort_t* wpt = wat + (size_t)C3 * C_;

    const int M = B_ * N_;

    // 0) conversions + weight transposes (single merged launch)
    prep<<<dim3(NCVT + NTA + NTP), dim3(256), 0, stream>>>(
        x, xb, w_attn, wat, w_proj, wpt);

    // 1) qkv projection: Q (pre-scaled 0.125*log2e), K -> qkb; V -> vtb transposed
    gemm_mfma<ushort_t, true><<<dim3(C3 / 128, M / 128), dim3(256), 0, stream>>>(
        xb, wat, b_attn, qkb, C2, vtb, M, C_, C3);

    // 2) attention -> y
    attn_mfma<<<dim3(B_ * H_ * 8), dim3(256), 0, stream>>>(qkb, vtb, pad, y);

    // 3) out = y @ w_proj + b_proj
    gemm_mfma<float, false><<<dim3(C_ / 128, M / 128), dim3(256), 0, stream>>>(
        y, wpt, b_proj, out, C_, nullptr, M, C_, C_);
}

// Round 7
// 186.311 us; speedup vs baseline: 1.2009x; 1.0354x over previous
//
#include <hip/hip_runtime.h>
#include <hip/hip_bf16.h>

// Problem constants (CausalSelfAttention_23768349016530)
#define B_  8
#define N_  1024
#define C_  768
#define H_  12
#define D_  64
#define C3  2304   // 3*C
#define C2  1536   // 2*C

typedef unsigned short ushort_t;
typedef __attribute__((ext_vector_type(8))) short bf16x8;   // 8 bf16 = 4 VGPR
typedef __attribute__((ext_vector_type(4))) float f32x4;    // MFMA 16x16 accumulator
typedef __attribute__((ext_vector_type(4))) unsigned int u32x4;

__device__ __forceinline__ ushort_t f2bf(float f) {
    union { float f; unsigned int i; } v;
    v.f = f;
    unsigned int x = v.i;
    if ((x & 0x7f800000u) == 0x7f800000u && (x & 0x007fffffu))
        return (ushort_t)((x >> 16) | 0x0040u);   // quiet NaN
    return (ushort_t)((x + 0x7fffu + ((x >> 16) & 1u)) >> 16);  // RNE
}

__device__ __forceinline__ void st1(float* p, float v) { *p = v; }
__device__ __forceinline__ void st1(ushort_t* p, float v) { *p = f2bf(v); }

// ---------------------------------------------------------------------------
// Merged prep kernel: fp32->bf16 convert of x, plus both weight transposes.
// ---------------------------------------------------------------------------
#define NCVT 6144            // (B*N*C) / (256*4)
#define NTA  1728            // (C3/32)*(C/32)
#define NTP  576             // (C/32)*(C/32)

__device__ __forceinline__ void transpose_tile(
    const float* __restrict__ W, ushort_t* __restrict__ WT,
    int K, int Nn, int n0, int k0, float (*t)[33], int tid)
{
    const int tx = tid & 31, ty = tid >> 5;   // ty: 0..7
    #pragma unroll
    for (int i = 0; i < 4; ++i) {
        const int k = ty + i * 8;
        t[k][tx] = W[(size_t)(k0 + k) * Nn + n0 + tx];
    }
    __syncthreads();
    #pragma unroll
    for (int i = 0; i < 4; ++i) {
        const int n = ty + i * 8;
        WT[(size_t)(n0 + n) * K + k0 + tx] = f2bf(t[tx][n]);
    }
}

__global__ __launch_bounds__(256) void prep(
    const float* __restrict__ X, ushort_t* __restrict__ Y,
    const float* __restrict__ Wa, ushort_t* __restrict__ WaT,
    const float* __restrict__ Wp, ushort_t* __restrict__ WpT)
{
    __shared__ float t[32][33];
    const int bid = blockIdx.x;
    const int tid = threadIdx.x;
    if (bid < NCVT) {
        const int i = (bid * 256 + tid) * 4;
        float4 f = *reinterpret_cast<const float4*>(X + i);
        ushort4 o;
        o.x = f2bf(f.x); o.y = f2bf(f.y); o.z = f2bf(f.z); o.w = f2bf(f.w);
        *reinterpret_cast<ushort4*>(Y + i) = o;
    } else if (bid < NCVT + NTA) {
        const int tt = bid - NCVT;
        transpose_tile(Wa, WaT, C_, C3, (tt % (C3 / 32)) * 32,
                       (tt / (C3 / 32)) * 32, t, tid);
    } else {
        const int tt = bid - NCVT - NTA;
        transpose_tile(Wp, WpT, C_, C_, (tt % (C_ / 32)) * 32,
                       (tt / (C_ / 32)) * 32, t, tid);
    }
}

// ---------------------------------------------------------------------------
// MFMA GEMM: 128x128 tile, BK=64, 256 thr, XOR-swizzled LDS, global_load_lds
// staging, bijective XCD chunk swizzle (T1).
// v7: DOUBLE-BUFFERED K-loop (T3 minimum-2-phase): stage tile t+1 BEFORE
// computing tile t; ONE __syncthreads per step. Its implicit vmcnt(0) now
// waits for loads that had the whole MFMA phase to land -> stage latency
// hidden without relying on TLP. LDS 64KB (2 blocks/CU).
// vtOut: V written transposed AND key-permuted within each 32-token group
// (pi(k) = (k&3) + 4*((k>>4)&1) + 8*((k>>2)&3)) so attn's PV B-fragment is
// one contiguous ds_read_b128 in the same conflict-free pattern as K.
// ---------------------------------------------------------------------------
#define GBK 64

__device__ __forceinline__ void gld_lds16(const ushort_t* g, ushort_t* lds) {
    __builtin_amdgcn_global_load_lds(
        (const __attribute__((address_space(1))) void*)g,
        (__attribute__((address_space(3))) void*)lds, 16, 0, 0);
}

template<typename TO, bool SCALEQ>
__global__ __launch_bounds__(256) void gemm_mfma(
    const ushort_t* __restrict__ A, const ushort_t* __restrict__ BT,
    const float* __restrict__ bias, TO* __restrict__ Y, int ldY,
    ushort_t* __restrict__ vtOut, int M, int K, int Nn)
{
    __shared__ ushort_t AB[2][2 * 128 * GBK];   // [buf][As|Bs], 64 KB

    const int tid  = threadIdx.x;
    const int wave = tid >> 6;
    const int lane = tid & 63;

    // XCD swizzle: hw block i runs on XCD i%8; give XCD k the contiguous
    // work-ids [k*chunk, (k+1)*chunk). Row-major work decode (nbx cols).
    const int nbx  = Nn / 128;
    const int nblk = nbx * (M / 128);
    const int hwid = blockIdx.y * gridDim.x + blockIdx.x;
    const int wid  = (hwid & 7) * (nblk >> 3) + (hwid >> 3);
    const int row0 = (wid / nbx) * 128;
    const int col0 = (wid % nbx) * 128;

    const int wr   = (wave >> 1) * 64;
    const int wc   = (wave & 1) * 64;
    const int l15  = lane & 15;
    const int quad = lane >> 4;
    const int l7   = l15 & 7;

    // staging: lane -> (row = base + lane>>3, slot = lane&7); fetch granule
    // slot^row so that LDS slot s holds granule s^(r&7).
    const int srow = lane >> 3;                 // 0..7
    const int sg   = (lane & 7) ^ srow;         // data granule to fetch

    f32x4 acc[4][4] = {};

    // prologue: stage k0=0 into buf 0
    #pragma unroll
    for (int it = 0; it < 4; ++it) {
        const int baseRow = wave * 32 + it * 8;               // wave-uniform
        const int r = baseRow + srow;
        gld_lds16(&A [(size_t)(row0 + r) * K + sg * 8], &AB[0][baseRow * GBK]);
        gld_lds16(&BT[(size_t)(col0 + r) * K + sg * 8],
                  &AB[0][128 * GBK + baseRow * GBK]);
    }
    __syncthreads();

    const int nsteps = K / GBK;
    for (int t = 0; t < nsteps; ++t) {
        const int buf = t & 1;
        const ushort_t* const As = AB[buf];
        const ushort_t* const Bs = AB[buf] + 128 * GBK;

        // issue next tile's loads into the other buffer (no wait)
        if (t + 1 < nsteps) {
            const int k0 = (t + 1) * GBK;
            #pragma unroll
            for (int it = 0; it < 4; ++it) {
                const int baseRow = wave * 32 + it * 8;
                const int r = baseRow + srow;
                gld_lds16(&A [(size_t)(row0 + r) * K + k0 + sg * 8],
                          &AB[buf ^ 1][baseRow * GBK]);
                gld_lds16(&BT[(size_t)(col0 + r) * K + k0 + sg * 8],
                          &AB[buf ^ 1][128 * GBK + baseRow * GBK]);
            }
        }

        #pragma unroll
        for (int kc = 0; kc < 2; ++kc) {
            bf16x8 af[4], bf[4];
            #pragma unroll
            for (int i = 0; i < 4; ++i) {
                const int aslot = (kc * 4 + quad) ^ l7;
                af[i] = *reinterpret_cast<const bf16x8*>(
                    &As[(wr + i * 16 + l15) * GBK + aslot * 8]);
                bf[i] = *reinterpret_cast<const bf16x8*>(
                    &Bs[(wc + i * 16 + l15) * GBK + aslot * 8]);
            }
            #pragma unroll
            for (int i = 0; i < 4; ++i)
                #pragma unroll
                for (int j = 0; j < 4; ++j)
                    acc[i][j] = __builtin_amdgcn_mfma_f32_16x16x32_bf16(
                        af[i], bf[j], acc[i][j], 0, 0, 0);
        }
        __syncthreads();   // drains next-tile DMA (hidden under MFMA) + barrier
    }

    // per-wave-column-tile uniform Q-scale (columns < C_ are Q)
    // 0.125 * log2(e) so attention can use v_exp_f32 (base-2) directly.
    const float qs = (SCALEQ && (col0 + wc) < C_) ? 0.1803368801f : 1.0f;

    if (vtOut != nullptr && col0 >= C2) {
        // V part: write transposed vt[b][h][d][pos], pos = key-permuted token
        #pragma unroll
        for (int i = 0; i < 4; ++i) {
            const int r0 = row0 + wr + i * 16 + quad * 4;   // token base
            const int bb = r0 >> 10;
            const int n  = r0 & 1023;
            // permuted position: pi(k)=(k&3)+4*((k>>4)&1)+8*((k>>2)&3);
            // here n%32 = (i&1)*16 + quad*4  ->  group base + 8*quad + 4*(i&1)
            const int np = (n & 0x3E0) | (quad << 3) | ((i & 1) << 2);
            #pragma unroll
            for (int j = 0; j < 4; ++j) {
                const int c  = col0 + wc + j * 16 + l15;
                const int cv = c - C2;
                const int hh = cv >> 6, d = cv & 63;
                const float bv = bias[c];
                ushort4 o;
                o.x = f2bf(acc[i][j][0] + bv);
                o.y = f2bf(acc[i][j][1] + bv);
                o.z = f2bf(acc[i][j][2] + bv);
                o.w = f2bf(acc[i][j][3] + bv);
                *reinterpret_cast<ushort4*>(
                    &vtOut[((size_t)(bb * H_ + hh) * D_ + d) * N_ + np]) = o;
            }
        }
    } else {
        #pragma unroll
        for (int i = 0; i < 4; ++i) {
            const int r = row0 + wr + i * 16 + quad * 4;
            #pragma unroll
            for (int j = 0; j < 4; ++j) {
                const int c = col0 + wc + j * 16 + l15;
                const float bv = bias[c];
                #pragma unroll
                for (int t = 0; t < 4; ++t)
                    st1(&Y[(size_t)(r + t) * ldY + c], (acc[i][j][t] + bv) * qs);
            }
        }
    }
}

// ---------------------------------------------------------------------------
// MFMA attention, v7 (= v6 + dbuf pipeline + b128 V reads + raw-sum den):
//  * double-buffered K/V tiles (32KB): stage tile t+1 before computing t,
//    ONE barrier per tile (same T3 recipe as the GEMM).
//  * vt is stored key-permuted by gemm1, so the PV B-fragment is a single
//    ds_read_b128 at slot (kc*4+quad)^l7 — identical conflict-free pattern
//    as the K reads. Replaces 16 b64 reads + shuffles per tile.
//  * den accumulates raw exp2 values (4 adds) instead of re-extracting the
//    quantized bf16 pair-words; adds ~1e-4 error vs 2.2e-3 threshold.
//  * swapped QK^T; in-register P pack (round-half-up, T0->lo); Q pre-scaled
//    0.125*log2e; T5 setprio; T1 XCD chunk swizzle; v6 epilogue fence.
// ---------------------------------------------------------------------------
__global__ __launch_bounds__(256) void attn_mfma(
    const ushort_t* __restrict__ qk, const ushort_t* __restrict__ vt,
    const int* __restrict__ pad_mask, ushort_t* __restrict__ y)
{
    __shared__ __align__(16) ushort_t KV[2][2 * 64 * 64];   // 32 KB dbuf

    const int tid  = threadIdx.x;
    const int wave = tid >> 6;
    const int lane = tid & 63;
    const int l15  = lane & 15;
    const int quad = lane >> 4;
    const int l7   = l15 & 7;

    // XCD swizzle: 768 blocks = 8 XCDs * 96; work-id chunk of 96 = one batch.
    const int wid = (blockIdx.x & 7) * 96 + (blockIdx.x >> 3);
    const int qt = wid & 7;                       // 8 q-tiles of 128
    const int hb = wid >> 3;
    const int h  = hb % H_;
    const int b  = hb / H_;
    const int q0 = qt * 128 + wave * 32;          // wave's first query row

    const ushort_t* qkB = qk + (size_t)b * N_ * C2;
    const ushort_t* vtB = vt + ((size_t)(b * H_ + h)) * D_ * N_;
    const int ho = h * D_;

    // Q fragments (B-operand): col=l15 -> q, k=quad*8 (+32*kc)
    bf16x8 qf[2][2];
    #pragma unroll
    for (int rt = 0; rt < 2; ++rt)
        #pragma unroll
        for (int kc = 0; kc < 2; ++kc)
            qf[rt][kc] = *reinterpret_cast<const bf16x8*>(
                &qkB[(size_t)(q0 + rt * 16 + l15) * C2 + ho + kc * 32 + quad * 8]);

    // pad mask per C-layout output row (q = rt*16 + quad*4 + t), epilogue only
    int mrow[2][4];
    #pragma unroll
    for (int rt = 0; rt < 2; ++rt)
        #pragma unroll
        for (int t = 0; t < 4; ++t)
            mrow[rt][t] = pad_mask[b * N_ + q0 + rt * 16 + quad * 4 + t];

    f32x4 oacc[2][4] = {};
    float den[2] = {};                  // per-lane partial (this quad's keys)

    // staging: per wave, rows wave*16 .. wave*16+15 of both K and Vt tiles.
    const int srow = lane >> 3;            // 0..7 within an 8-row group
    const int sg   = (lane & 7) ^ srow;    // swizzled source granule (16B)

    // prologue: stage tile 0 into buf 0
    #pragma unroll
    for (int it = 0; it < 2; ++it) {
        const int base = wave * 16 + it * 8;              // wave-uniform
        const int r = base + srow;
        gld_lds16(&qkB[(size_t)r * C2 + C_ + ho + sg * 8], &KV[0][base * 64]);
        gld_lds16(&vtB[(size_t)r * N_ + sg * 8], &KV[0][4096 + base * 64]);
    }
    __syncthreads();

    for (int t = 0; t < N_ / 64; ++t) {
        const int buf = t & 1;
        const ushort_t* const Ks  = KV[buf];
        const ushort_t* const Vts = KV[buf] + 4096;

        // issue next tile's loads into the other buffer (no wait)
        if (t + 1 < N_ / 64) {
            const int k0 = (t + 1) * 64;
            #pragma unroll
            for (int it = 0; it < 2; ++it) {
                const int base = wave * 16 + it * 8;
                const int r = base + srow;
                gld_lds16(&qkB[(size_t)(k0 + r) * C2 + C_ + ho + sg * 8],
                          &KV[buf ^ 1][base * 64]);
                gld_lds16(&vtB[(size_t)r * N_ + k0 + sg * 8],
                          &KV[buf ^ 1][4096 + base * 64]);
            }
        }

        // S^T = K Q^T (swapped operands): lane holds
        // s[rt][ct][t] = S[key = ct*16+quad*4+t][q = rt*16+l15]
        f32x4 s[2][4] = {};
        #pragma unroll
        for (int kc = 0; kc < 2; ++kc) {
            bf16x8 kf[4];
            #pragma unroll
            for (int ct = 0; ct < 4; ++ct) {
                const int slot = (kc * 4 + quad) ^ l7;
                kf[ct] = *reinterpret_cast<const bf16x8*>(
                    &Ks[(ct * 16 + l15) * 64 + slot * 8]);
            }
            __builtin_amdgcn_s_setprio(1);
            #pragma unroll
            for (int rt = 0; rt < 2; ++rt)
                #pragma unroll
                for (int ct = 0; ct < 4; ++ct)
                    s[rt][ct] = __builtin_amdgcn_mfma_f32_16x16x32_bf16(
                        kf[ct], qf[rt][kc], s[rt][ct], 0, 0, 0);
            __builtin_amdgcn_s_setprio(0);
        }

        // P = 2^S; quantize round-half-up to bf16, pack pairs (T0 -> lo).
        // den sums the RAW exp2 values (normalization error ~1e-4, in budget).
        unsigned pk[2][4][2];
        #pragma unroll
        for (int rt = 0; rt < 2; ++rt)
            #pragma unroll
            for (int ct = 0; ct < 4; ++ct) {
                const float p0 = __builtin_amdgcn_exp2f(s[rt][ct][0]);
                const float p1 = __builtin_amdgcn_exp2f(s[rt][ct][1]);
                const float p2 = __builtin_amdgcn_exp2f(s[rt][ct][2]);
                const float p3 = __builtin_amdgcn_exp2f(s[rt][ct][3]);
                den[rt] += (p0 + p1) + (p2 + p3);
                const unsigned x0 = __float_as_uint(p0) + 0x8000u;
                const unsigned x1 = __float_as_uint(p1) + 0x8000u;
                const unsigned x2 = __float_as_uint(p2) + 0x8000u;
                const unsigned x3 = __float_as_uint(p3) + 0x8000u;
                pk[rt][ct][0] = (x0 >> 16) | (x1 & 0xffff0000u);
                pk[rt][ct][1] = (x2 >> 16) | (x3 & 0xffff0000u);
            }

        // O += P V. V is key-permuted in memory so B-fragment = one b128 at
        // the K-style slot; A (packed P) slot j holds the matching key.
        #pragma unroll
        for (int kc = 0; kc < 2; ++kc) {
            bf16x8 pf[2], vf[4];
            #pragma unroll
            for (int rt = 0; rt < 2; ++rt) {
                const u32x4 pw = (u32x4){pk[rt][kc * 2][0], pk[rt][kc * 2][1],
                                         pk[rt][kc * 2 + 1][0],
                                         pk[rt][kc * 2 + 1][1]};
                pf[rt] = __builtin_bit_cast(bf16x8, pw);
            }
            #pragma unroll
            for (int dt = 0; dt < 4; ++dt) {
                const int slot = (kc * 4 + quad) ^ l7;
                vf[dt] = *reinterpret_cast<const bf16x8*>(
                    &Vts[(dt * 16 + l15) * 64 + slot * 8]);
            }
            __builtin_amdgcn_s_setprio(1);
            #pragma unroll
            for (int rt = 0; rt < 2; ++rt)
                #pragma unroll
                for (int dt = 0; dt < 4; ++dt)
                    oacc[rt][dt] = __builtin_amdgcn_mfma_f32_16x16x32_bf16(
                        pf[rt], vf[dt], oacc[rt][dt], 0, 0, 0);
            __builtin_amdgcn_s_setprio(0);
        }
        __syncthreads();   // drains next-tile DMA (hidden under compute)
    }

    // epilogue: reduce den across quads, normalize, stage O in freed LDS
    // (XOR-swizzled rows, stride 64), emit 16B stores.
    ushort_t* const scratch = KV[0] + wave * 32 * 64;   // wave-private rows

    #pragma unroll
    for (int rt = 0; rt < 2; ++rt) {
        float v = den[rt];
        v += __shfl_xor(v, 16);
        v += __shfl_xor(v, 32);
        den[rt] = v;                  // full denom for q = rt*16+l15, all lanes
    }
    #pragma unroll
    for (int rt = 0; rt < 2; ++rt)
        #pragma unroll
        for (int t = 0; t < 4; ++t) {
            const float dv  = __shfl(den[rt], quad * 4 + t);
            const float inv = mrow[rt][t] ? 1.0f / dv : __builtin_nanf("");
            const int row = rt * 16 + quad * 4 + t;          // 0..31
            #pragma unroll
            for (int dt = 0; dt < 4; ++dt) {
                const int slot = (dt * 2 + (l15 >> 3)) ^ (row & 7);
                scratch[row * 64 + slot * 8 + l7] =
                    f2bf(oacc[rt][dt][t] * inv);
            }
        }
    // architectural fence between scalar scratch writes and vector re-reads
    __syncthreads();
    {
        const int orow = lane >> 1;               // 0..31
        const int og   = (lane & 1) * 4;          // granule base: 0 or 4
        const size_t gr = (size_t)(b * N_ + q0 + orow) * C_ + ho;
        #pragma unroll
        for (int i2 = 0; i2 < 4; ++i2) {
            const int g = og + i2;
            uint4 w = *reinterpret_cast<const uint4*>(
                &scratch[orow * 64 + (g ^ (orow & 7)) * 8]);
            *reinterpret_cast<uint4*>(&y[gr + g * 8]) = w;
        }
    }
}

// ---------------------------------------------------------------------------
extern "C" void kernel_launch(void* const* d_in, const int* in_sizes, int n_in,
                              void* d_out, int out_size, void* d_ws, size_t ws_size,
                              hipStream_t stream)
{
    const float* x      = (const float*)d_in[0];
    const int*   pad    = (const int*)d_in[1];
    const float* w_attn = (const float*)d_in[2];
    const float* b_attn = (const float*)d_in[3];
    const float* w_proj = (const float*)d_in[4];
    const float* b_proj = (const float*)d_in[5];
    float* out = (float*)d_out;

    // ws (bf16 elems): qk [B*N,2C] | vt [B,H,D,N] | y(=xb) [B*N,C] | wat | wpt
    ushort_t* qkb = (ushort_t*)d_ws;
    ushort_t* vtb = qkb + (size_t)B_ * N_ * C2;
    ushort_t* y   = vtb + (size_t)B_ * H_ * D_ * N_;
    ushort_t* xb  = y;   // consumed by gemm1 before attn overwrites with y
    ushort_t* wat = y + (size_t)B_ * N_ * C_;
    ushort_t* wpt = wat + (size_t)C3 * C_;

    const int M = B_ * N_;

    // 0) conversions + weight transposes (single merged launch)
    prep<<<dim3(NCVT + NTA + NTP), dim3(256), 0, stream>>>(
        x, xb, w_attn, wat, w_proj, wpt);

    // 1) qkv projection: Q (pre-scaled 0.125*log2e), K -> qkb; V -> vtb
    //    transposed + key-permuted
    gemm_mfma<ushort_t, true><<<dim3(C3 / 128, M / 128), dim3(256), 0, stream>>>(
        xb, wat, b_attn, qkb, C2, vtb, M, C_, C3);

    // 2) attention -> y
    attn_mfma<<<dim3(B_ * H_ * 8), dim3(256), 0, stream>>>(qkb, vtb, pad, y);

    // 3) out = y @ w_proj + b_proj
    gemm_mfma<float, false><<<dim3(C_ / 128, M / 128), dim3(256), 0, stream>>>(
        y, wpt, b_proj, out, C_, nullptr, M, C_, C_);
}